// Round 1
// baseline (121.076 us; speedup 1.0000x reference)
//
#include <hip/hip_runtime.h>

// YOLO-v1 style loss, fully fused single pass.
// pred: (8192,7,7,30) f32, gt: (8192,7,7,30) f32 -> scalar f32 (= total/8192).
//
// Memory-bound: 96.3 MB in, 4 B out. Strategy: coalesced float4 staging of
// 256-cell tiles (30 floats/cell) into LDS with pad-31 stride (conflict-free
// compute reads), per-cell loss in registers, wave64 shuffle reduce,
// one atomicAdd per block.

#define NCH 30
#define CPB 256      // cells per block
#define TPB 256
#define PAD 31       // LDS row stride (gcd(31,32)=1 -> conflict-free)
#define INV_B (1.0f / 8192.0f)

__global__ __launch_bounds__(TPB, 2)
void yolo_loss_kernel(const float* __restrict__ pred,
                      const float* __restrict__ gt,
                      float* __restrict__ out,
                      int ncells)
{
    __shared__ float sp[CPB * PAD];
    __shared__ float sg[CPB * PAD];
    __shared__ float wsum[TPB / 64];

    const int tid = threadIdx.x;
    const long long cellBase = (long long)blockIdx.x * CPB;
    const long long elemBase = cellBase * NCH;
    const long long totalElems = (long long)ncells * NCH;

    // ---- stage: 256 cells * 30 floats = 7680 floats = 1920 float4 per input
    const float4* p4 = (const float4*)(pred + elemBase);
    const float4* g4 = (const float4*)(gt + elemBase);
    const int nvec = (CPB * NCH) / 4;   // 1920
    for (int i = tid; i < nvec; i += TPB) {
        long long gidx = elemBase + (long long)i * 4;
        if (gidx + 3 < totalElems) {
            float4 vp = p4[i];
            float4 vg = g4[i];
            float ap[4] = {vp.x, vp.y, vp.z, vp.w};
            float ag[4] = {vg.x, vg.y, vg.z, vg.w};
#pragma unroll
            for (int k = 0; k < 4; ++k) {
                int idx = i * 4 + k;          // flat = cell*30 + ch
                int lidx = idx + idx / NCH;   // -> cell*31 + ch
                sp[lidx] = ap[k];
                sg[lidx] = ag[k];
            }
        }
    }
    __syncthreads();

    // ---- per-cell loss
    float cell_loss = 0.0f;
    const long long cell = cellBase + tid;
    if (cell < ncells) {
        const float* cp = &sp[tid * PAD];
        const float* cg = &sg[tid * PAD];

        const float gc = cg[4];                     // obj flag (0 or 1 exactly)
        const float obj = (gc > 0.0f) ? 1.0f : 0.0f;
        const float noobj = (gc == 0.0f) ? 1.0f : 0.0f;

        const float gx = cg[0], gy = cg[1], gw = cg[2], gh = cg[3];
        const float ghw = 3.5f * gw, ghh = 3.5f * gh;   // 0.5*GRID*wh
        const float a2 = 49.0f * gw * gh;

        float iou[2], pc[2];
#pragma unroll
        for (int k = 0; k < 2; ++k) {
            const int b = k * 5;
            const float px = cp[b + 0], py = cp[b + 1];
            const float pw = cp[b + 2], ph = cp[b + 3];
            pc[k] = cp[b + 4];
            const float phw = 3.5f * pw, phh = 3.5f * ph;
            const float ltx = fmaxf(px - phw, gx - ghw);
            const float rbx = fminf(px + phw, gx + ghw);
            const float lty = fmaxf(py - phh, gy - ghh);
            const float rby = fminf(py + phh, gy + ghh);
            const float w = fmaxf(rbx - ltx, 0.0f);
            const float h = fmaxf(rby - lty, 0.0f);
            const float inter = w * h;
            const float a1 = 49.0f * pw * ph;
            iou[k] = inter / (a1 + a2 - inter);
        }

        // argmax with first-max tie-break: box1 wins only if strictly greater
        const int r = (iou[1] > iou[0]) ? 1 : 0;
        const float max_iou = fmaxf(iou[0], iou[1]);

        const int rb = r * 5;
        const float dx = cp[rb + 0] - gx;
        const float dy = cp[rb + 1] - gy;
        const float dw = sqrtf(cp[rb + 2]) - sqrtf(gw);
        const float dh = sqrtf(cp[rb + 3]) - sqrtf(gh);
        const float coord = dx * dx + dy * dy + dw * dw + dh * dh;

        float d = pc[r] - max_iou;
        const float resp_l = d * d;
        const float irr_l = pc[1 - r] * pc[1 - r];

        const float d0 = pc[0] - gc, d1 = pc[1] - gc;
        const float noobj_l = d0 * d0 + d1 * d1;

        float cls = 0.0f;
#pragma unroll
        for (int c = 0; c < 20; ++c) {
            const float e = cp[10 + c] - cg[10 + c];
            cls += e * e;
        }

        // total = 5*coord + 2*resp + 0.5*noobj + cls + irr  (resp counted twice)
        cell_loss = obj * (5.0f * coord + 2.0f * resp_l + irr_l + cls)
                  + noobj * 0.5f * noobj_l;
    }

    // ---- reduce: wave64 shuffle, then block, then one atomic
    float v = cell_loss * INV_B;
#pragma unroll
    for (int off = 32; off > 0; off >>= 1)
        v += __shfl_down(v, off, 64);
    if ((tid & 63) == 0) wsum[tid >> 6] = v;
    __syncthreads();
    if (tid == 0) {
        float s = 0.0f;
#pragma unroll
        for (int w = 0; w < TPB / 64; ++w) s += wsum[w];
        atomicAdd(out, s);
    }
}

extern "C" void kernel_launch(void* const* d_in, const int* in_sizes, int n_in,
                              void* d_out, int out_size, void* d_ws, size_t ws_size,
                              hipStream_t stream)
{
    const float* pred = (const float*)d_in[0];
    const float* gt   = (const float*)d_in[1];
    float* out = (float*)d_out;

    const int ncells = in_sizes[0] / NCH;           // 8192*49 = 401408
    const int nblocks = (ncells + CPB - 1) / CPB;   // 1568

    hipMemsetAsync(out, 0, sizeof(float), stream);
    yolo_loss_kernel<<<nblocks, TPB, 0, stream>>>(pred, gt, out, ncells);
}

// Round 2
// 118.632 us; speedup vs baseline: 1.0206x; 1.0206x over previous
//
#include <hip/hip_runtime.h>

// YOLO-v1 style loss, fully fused single pass, LDS-free.
// pred: (8192,7,7,30) f32, gt: (8192,7,7,30) f32 -> scalar f32 (= total/8192).
//
// R1 post-mortem: LDS-staged version was latency-bound (occ 15%, VALU 13%,
// 1.15 TB/s) -- 62.5 KB LDS capped 2 blocks/CU. This version reads each
// 120-byte cell record directly as 15 float2 loads (8B-aligned, stride-120
// across lanes; neighboring lanes fully consume every cacheline via L1).
// No LDS -> occupancy bounded only by VGPRs (~5 waves/SIMD), 28 independent
// loads/thread for deep MLP.

#define NCH 30
#define TPB 256
#define INV_B (1.0f / 8192.0f)

__global__ __launch_bounds__(TPB)
void yolo_loss_kernel(const float* __restrict__ pred,
                      const float* __restrict__ gt,
                      float* __restrict__ out,
                      int ncells)
{
    __shared__ float wsum[TPB / 64];

    const int tid = threadIdx.x;
    const int cell = blockIdx.x * TPB + tid;

    float cell_loss = 0.0f;
    if (cell < ncells) {
        const float* cp = pred + (long long)cell * NCH;
        const float* cg = gt + (long long)cell * NCH;

        // ---- load pred: all 30 channels as 15 float2 (independent loads)
        float2 p[15];
#pragma unroll
        for (int j = 0; j < 15; ++j)
            p[j] = *(const float2*)(cp + 2 * j);

        // ---- load gt: box (ch 0..5) + classes (ch 10..29); skip dup box ch 6..9
        float2 g0 = *(const float2*)(cg + 0);
        float2 g1 = *(const float2*)(cg + 2);
        float2 g2 = *(const float2*)(cg + 4);   // .x = obj flag
        float2 gcl[10];
#pragma unroll
        for (int j = 0; j < 10; ++j)
            gcl[j] = *(const float2*)(cg + 10 + 2 * j);

        const float gx = g0.x, gy = g0.y, gw = g1.x, gh = g1.y;
        const float gc = g2.x;
        const float obj = (gc > 0.0f) ? 1.0f : 0.0f;
        const float noobj = (gc == 0.0f) ? 1.0f : 0.0f;

        const float ghw = 3.5f * gw, ghh = 3.5f * gh;   // 0.5*GRID*wh
        const float a2 = 49.0f * gw * gh;

        // pred boxes
        const float px[2] = {p[0].x, p[2].y};
        const float py[2] = {p[0].y, p[3].x};
        const float pw[2] = {p[1].x, p[3].y};
        const float ph[2] = {p[1].y, p[4].x};
        const float pc[2] = {p[2].x, p[4].y};

        float iou[2];
#pragma unroll
        for (int k = 0; k < 2; ++k) {
            const float phw = 3.5f * pw[k], phh = 3.5f * ph[k];
            const float ltx = fmaxf(px[k] - phw, gx - ghw);
            const float rbx = fminf(px[k] + phw, gx + ghw);
            const float lty = fmaxf(py[k] - phh, gy - ghh);
            const float rby = fminf(py[k] + phh, gy + ghh);
            const float w = fmaxf(rbx - ltx, 0.0f);
            const float h = fmaxf(rby - lty, 0.0f);
            const float inter = w * h;
            const float a1 = 49.0f * pw[k] * ph[k];
            iou[k] = inter / (a1 + a2 - inter);
        }

        // argmax with first-max tie-break: box1 wins only if strictly greater
        const int r = (iou[1] > iou[0]) ? 1 : 0;
        const float max_iou = fmaxf(iou[0], iou[1]);

        const float dx = px[r] - gx;
        const float dy = py[r] - gy;
        const float dw = sqrtf(pw[r]) - sqrtf(gw);
        const float dh = sqrtf(ph[r]) - sqrtf(gh);
        const float coord = dx * dx + dy * dy + dw * dw + dh * dh;

        const float d = pc[r] - max_iou;
        const float resp_l = d * d;
        const float irr_l = pc[1 - r] * pc[1 - r];

        const float d0 = pc[0] - gc, d1 = pc[1] - gc;
        const float noobj_l = d0 * d0 + d1 * d1;

        float cls = 0.0f;
#pragma unroll
        for (int j = 0; j < 10; ++j) {
            const float ex = p[5 + j].x - gcl[j].x;
            const float ey = p[5 + j].y - gcl[j].y;
            cls += ex * ex + ey * ey;
        }

        // total = 5*coord + 2*resp + 0.5*noobj + cls + irr  (resp counted twice)
        cell_loss = obj * (5.0f * coord + 2.0f * resp_l + irr_l + cls)
                  + noobj * 0.5f * noobj_l;
    }

    // ---- reduce: wave64 shuffle, then block, then one atomic
    float v = cell_loss * INV_B;
#pragma unroll
    for (int off = 32; off > 0; off >>= 1)
        v += __shfl_down(v, off, 64);
    if ((tid & 63) == 0) wsum[tid >> 6] = v;
    __syncthreads();
    if (tid == 0) {
        float s = 0.0f;
#pragma unroll
        for (int w = 0; w < TPB / 64; ++w) s += wsum[w];
        atomicAdd(out, s);
    }
}

extern "C" void kernel_launch(void* const* d_in, const int* in_sizes, int n_in,
                              void* d_out, int out_size, void* d_ws, size_t ws_size,
                              hipStream_t stream)
{
    const float* pred = (const float*)d_in[0];
    const float* gt   = (const float*)d_in[1];
    float* out = (float*)d_out;

    const int ncells = in_sizes[0] / NCH;           // 8192*49 = 401408
    const int nblocks = (ncells + TPB - 1) / TPB;   // 1568

    hipMemsetAsync(out, 0, sizeof(float), stream);
    yolo_loss_kernel<<<nblocks, TPB, 0, stream>>>(pred, gt, out, ncells);
}